// Round 1
// baseline (516.863 us; speedup 1.0000x reference)
//
#include <hip/hip_runtime.h>
#include <hip/hip_bf16.h>

#define Nn 200000
#define Cc 1000
#define Dd 256

typedef float f32x4v __attribute__((ext_vector_type(4)));
typedef short bf16x8 __attribute__((ext_vector_type(8)));

__device__ __forceinline__ unsigned short f2bf(float x){
    union { float f; unsigned int u; } c; c.f = x;
    unsigned int u = c.u;
    u += 0x7fffu + ((u >> 16) & 1u);   // round-to-nearest-even
    return (unsigned short)(u >> 16);
}

// ---------------- weight prep: Wcat_t[col][k] bf16, col 0..255 = Wk, 256..511 = H1w ----------------
__global__ void k_prep_wcat(const float* __restrict__ Wk, const float* __restrict__ H1w,
                            unsigned short* __restrict__ wcat){
    int i = blockIdx.x * 256 + threadIdx.x;       // 512 blocks x 256
    int col = i >> 8, k = i & 255;
    float w = (col < Dd) ? Wk[k*Dd + col] : H1w[k*Dd + (col - Dd)];
    wcat[col*Dd + k] = f2bf(w);
}

// ---------------- per-cluster precompute: qb = g@Wq + b_attn ; h_trans = tanh(g@Ws+bs) ;
//                  cterm = h_trans@G1w + G1b + H1b ----------------
__global__ void k_cluster_prep(const float* __restrict__ g, const float* __restrict__ Wq,
                               const float* __restrict__ b_attn,
                               const float* __restrict__ Ws, const float* __restrict__ bs,
                               const float* __restrict__ G1w, const float* __restrict__ G1b,
                               const float* __restrict__ H1b,
                               float* __restrict__ qb, float* __restrict__ h_trans,
                               float* __restrict__ cterm){
    int c = blockIdx.x, d = threadIdx.x;
    __shared__ float gL[Dd], htL[Dd];
    gL[d] = g[c*Dd + d];
    __syncthreads();
    float aq = b_attn[d], as = bs[d];
    for (int k = 0; k < Dd; ++k){
        float gv = gL[k];
        aq = fmaf(gv, Wq[k*Dd + d], aq);
        as = fmaf(gv, Ws[k*Dd + d], as);
    }
    qb[c*Dd + d] = aq;
    float ht = tanhf(as);
    h_trans[c*Dd + d] = ht;
    htL[d] = ht;
    __syncthreads();
    float ac = H1b[d] + G1b[d];
    for (int k = 0; k < Dd; ++k) ac = fmaf(htL[k], G1w[k*Dd + d], ac);
    cterm[c*Dd + d] = ac;
}

// ---------------- counting sort of nodes by cluster ----------------
__global__ void k_zero(int* __restrict__ hist){
    int i = blockIdx.x*256 + threadIdx.x;
    if (i < Cc) hist[i] = 0;
}
__global__ void k_hist(const int* __restrict__ seg, int* __restrict__ hist){
    int i = blockIdx.x*256 + threadIdx.x;
    if (i < Nn) atomicAdd(&hist[seg[i]], 1);
}
__global__ void k_scan(const int* __restrict__ hist, int* __restrict__ offs, int* __restrict__ cursor){
    __shared__ int sc[1024];
    int t = threadIdx.x;
    int v = (t < Cc) ? hist[t] : 0;
    sc[t] = v;
    __syncthreads();
    for (int off = 1; off < 1024; off <<= 1){
        int add = (t >= off) ? sc[t - off] : 0;
        __syncthreads();
        sc[t] += add;
        __syncthreads();
    }
    if (t < Cc){
        int excl = sc[t] - v;
        offs[t] = excl;
        cursor[t] = excl;
    }
}
__global__ void k_scatter(const int* __restrict__ seg, int* __restrict__ cursor, int* __restrict__ order){
    int i = blockIdx.x*256 + threadIdx.x;
    if (i < Nn){
        int p = atomicAdd(&cursor[seg[i]], 1);
        order[p] = i;
    }
}

// ---------------- the big fused kernel: Y = h_bf16 @ [Wk|H1w]  (64 rows x 512 cols / block)
//                  epilogue: e = exp(s)  and  h_merged -> out rows 0..N-1 ----------------
__global__ __launch_bounds__(512)
void k_gemm_fused(const float* __restrict__ h,
                  const unsigned short* __restrict__ wcat,
                  const int* __restrict__ seg,
                  const float* __restrict__ qb,
                  const float* __restrict__ w_score,
                  const float* __restrict__ b_score,
                  const float* __restrict__ cterm,
                  const float* __restrict__ h_trans,
                  float* __restrict__ e,
                  float* __restrict__ out){
    __shared__ unsigned short aT[64*256];   // 32 KiB, XOR-swizzled
    __shared__ float sPart[64][4];
    __shared__ int segL[64];

    int tid = threadIdx.x;
    int w = tid >> 6, l = tid & 63;
    int rowBase = blockIdx.x * 64;

    // stage A tile fp32 -> bf16 (coalesced float4 reads, swizzled 8B LDS writes)
    const float4* hv = reinterpret_cast<const float4*>(h + (size_t)rowBase * Dd);
    #pragma unroll
    for (int j = 0; j < 8; ++j){
        int f = j*512 + tid;              // float4 id in 64x256 tile
        int row = f >> 6;
        int k4  = (f & 63) << 2;
        float4 v = hv[f];
        unsigned long long pk = (unsigned long long)f2bf(v.x)
                              | ((unsigned long long)f2bf(v.y) << 16)
                              | ((unsigned long long)f2bf(v.z) << 32)
                              | ((unsigned long long)f2bf(v.w) << 48);
        int byte = (row*512 + k4*2) ^ ((row & 7) << 4);
        *reinterpret_cast<unsigned long long*>(reinterpret_cast<char*>(aT) + byte) = pk;
    }
    if (tid < 64) segL[tid] = seg[rowBase + tid];
    __syncthreads();

    int grp = l >> 4, rlo = l & 15;
    int wcol = w * 64;

    f32x4v acc[4][4];
    #pragma unroll
    for (int mt = 0; mt < 4; ++mt)
        #pragma unroll
        for (int nt = 0; nt < 4; ++nt)
            acc[mt][nt] = (f32x4v){0.f, 0.f, 0.f, 0.f};

    #pragma unroll
    for (int kk = 0; kk < 8; ++kk){
        bf16x8 aF[4], bF[4];
        int k0 = kk*32 + grp*8;
        #pragma unroll
        for (int mt = 0; mt < 4; ++mt){
            int row = mt*16 + rlo;
            int byte = (row*512 + k0*2) ^ ((row & 7) << 4);
            aF[mt] = *reinterpret_cast<const bf16x8*>(reinterpret_cast<const char*>(aT) + byte);
        }
        #pragma unroll
        for (int nt = 0; nt < 4; ++nt){
            int col = wcol + nt*16 + rlo;
            bF[nt] = *reinterpret_cast<const bf16x8*>(wcat + (size_t)col*Dd + k0);  // L2-resident B
        }
        #pragma unroll
        for (int mt = 0; mt < 4; ++mt)
            #pragma unroll
            for (int nt = 0; nt < 4; ++nt)
                acc[mt][nt] = __builtin_amdgcn_mfma_f32_16x16x32_bf16(aF[mt], bF[nt], acc[mt][nt], 0, 0, 0);
    }

    if (w < 4){
        // score half: cols 0..255 hold k = h@Wk. Row-reduce tanh(k + qb[seg])*w_score.
        int cols[4]; float wsc[4];
        #pragma unroll
        for (int nt = 0; nt < 4; ++nt){ cols[nt] = wcol + nt*16 + rlo; wsc[nt] = w_score[cols[nt]]; }
        #pragma unroll
        for (int mt = 0; mt < 4; ++mt){
            #pragma unroll
            for (int r = 0; r < 4; ++r){
                int row = mt*16 + grp*4 + r;
                const float* qrow = qb + (size_t)segL[row]*Dd;
                float p = 0.f;
                #pragma unroll
                for (int nt = 0; nt < 4; ++nt){
                    float y = acc[mt][nt][r] + qrow[cols[nt]];
                    p = fmaf(tanhf(y), wsc[nt], p);
                }
                p += __shfl_xor(p, 1);
                p += __shfl_xor(p, 2);
                p += __shfl_xor(p, 4);
                p += __shfl_xor(p, 8);
                if (rlo == 0) sPart[row][w] = p;
            }
        }
    }
    __syncthreads();
    if (w == 0){
        float sv = sPart[l][0] + sPart[l][1] + sPart[l][2] + sPart[l][3] + b_score[0];
        e[rowBase + l] = expf(sv);   // unshifted exp: |s| <= ~10, safe; ratio identical to ref
    }
    if (w >= 4){
        // merge half: cols 256..511 hold h@H1w. z1 = sigmoid(. + cterm[seg]); gated merge.
        int cols[4];
        #pragma unroll
        for (int nt = 0; nt < 4; ++nt) cols[nt] = (wcol - 256) + nt*16 + rlo;
        #pragma unroll
        for (int mt = 0; mt < 4; ++mt){
            #pragma unroll
            for (int r = 0; r < 4; ++r){
                int row = mt*16 + grp*4 + r;
                int sg = segL[row];
                const float* ct = cterm   + (size_t)sg*Dd;
                const float* ht = h_trans + (size_t)sg*Dd;
                const float* hr = h   + (size_t)(rowBase + row)*Dd;
                float* orow     = out + (size_t)(rowBase + row)*Dd;
                #pragma unroll
                for (int nt = 0; nt < 4; ++nt){
                    int c0 = cols[nt];
                    float z = 1.f / (1.f + expf(-(acc[mt][nt][r] + ct[c0])));
                    orow[c0] = (1.f - z)*hr[c0] + z*ht[c0];
                }
            }
        }
    }
}

// ---------------- per-cluster ctx = sum(e*h)/sum(e) over sorted node lists ----------------
__global__ void k_ctx(const float* __restrict__ h, const float* __restrict__ e,
                      const int* __restrict__ order, const int* __restrict__ hist,
                      const int* __restrict__ offs, float* __restrict__ ctx){
    int c = blockIdx.x, d = threadIdx.x;
    __shared__ int idxL[1024];
    __shared__ float eL[1024];
    __shared__ float red[256];
    int cnt = hist[c], start = offs[c];
    float acc = 0.f, dpart = 0.f;
    for (int base = 0; base < cnt; base += 1024){
        int m = min(1024, cnt - base);
        for (int i = d; i < m; i += 256){
            int n = order[start + base + i];
            idxL[i] = n;
            float ev = e[n];
            eL[i] = ev;
            dpart += ev;
        }
        __syncthreads();
        for (int i = 0; i < m; ++i)
            acc = fmaf(eL[i], h[(size_t)idxL[i]*Dd + d], acc);
        __syncthreads();
    }
    red[d] = dpart;
    for (int s_ = 128; s_ > 0; s_ >>= 1){
        __syncthreads();
        if (d < s_) red[d] += red[d + s_];
    }
    __syncthreads();
    float denom = red[0];
    float inv = (denom > 0.f) ? 1.f/denom : 0.f;   // empty cluster -> ctx = 0 (matches ref)
    ctx[c*Dd + d] = acc * inv;
}

// ---------------- virtual-node side: g_trans = tanh(ctx@Wv+bv); z2 gate; out rows N..N+C-1 ----------------
__global__ void k_vn(const float* __restrict__ ctx, const float* __restrict__ g_hat,
                     const float* __restrict__ Wv, const float* __restrict__ bv,
                     const float* __restrict__ H2w, const float* __restrict__ H2b,
                     const float* __restrict__ G2w, const float* __restrict__ G2b,
                     float* __restrict__ out){
    int c = blockIdx.x, d = threadIdx.x;
    __shared__ float cL[Dd], gtL[Dd], ghL[Dd];
    cL[d]  = ctx[c*Dd + d];
    ghL[d] = g_hat[c*Dd + d];
    __syncthreads();
    float a1 = bv[d];
    for (int k = 0; k < Dd; ++k) a1 = fmaf(cL[k], Wv[k*Dd + d], a1);
    float gt = tanhf(a1);
    gtL[d] = gt;
    __syncthreads();
    float a2 = H2b[d] + G2b[d];
    for (int k = 0; k < Dd; ++k){
        a2 = fmaf(gtL[k], H2w[k*Dd + d], a2);
        a2 = fmaf(ghL[k], G2w[k*Dd + d], a2);
    }
    float z = 1.f / (1.f + expf(-a2));
    out[(size_t)(Nn + c)*Dd + d] = (1.f - z)*gt + z*ghL[d];
}

extern "C" void kernel_launch(void* const* d_in, const int* in_sizes, int n_in,
                              void* d_out, int out_size, void* d_ws, size_t ws_size,
                              hipStream_t stream){
    const float* h       = (const float*)d_in[0];
    const float* g       = (const float*)d_in[1];
    const float* g_hat   = (const float*)d_in[2];
    const int*   seg     = (const int*)  d_in[3];
    const float* Wq      = (const float*)d_in[4];
    const float* Wk      = (const float*)d_in[5];
    const float* b_attn  = (const float*)d_in[6];
    const float* w_score = (const float*)d_in[7];
    const float* b_score = (const float*)d_in[8];
    const float* Wv      = (const float*)d_in[9];
    const float* bv      = (const float*)d_in[10];
    const float* Ws      = (const float*)d_in[11];
    const float* bs      = (const float*)d_in[12];
    const float* H1w     = (const float*)d_in[13];
    const float* H1b     = (const float*)d_in[14];
    const float* G1w     = (const float*)d_in[15];
    const float* G1b     = (const float*)d_in[16];
    const float* H2w     = (const float*)d_in[17];
    const float* H2b     = (const float*)d_in[18];
    const float* G2w     = (const float*)d_in[19];
    const float* G2b     = (const float*)d_in[20];
    float* out = (float*)d_out;

    char* ws = (char*)d_ws;
    unsigned short* wcat = (unsigned short*)(ws + 0);        // 262144 B
    float* qb      = (float*)(ws + 262144);                  // 1,024,000 B
    float* h_trans = (float*)(ws + 1286144);                 // 1,024,000 B
    float* cterm   = (float*)(ws + 2310144);                 // 1,024,000 B
    float* ctx     = (float*)(ws + 3334144);                 // 1,024,000 B
    float* e       = (float*)(ws + 4358144);                 //   800,000 B
    int*   order   = (int*)  (ws + 5158144);                 //   800,000 B
    int*   hist    = (int*)  (ws + 5958144);                 //     4,000 B
    int*   offs    = (int*)  (ws + 5962240);                 //     4,000 B
    int*   cursor  = (int*)  (ws + 5966336);                 //     4,000 B

    hipLaunchKernelGGL(k_prep_wcat, dim3(512), dim3(256), 0, stream, Wk, H1w, wcat);
    hipLaunchKernelGGL(k_cluster_prep, dim3(Cc), dim3(256), 0, stream,
                       g, Wq, b_attn, Ws, bs, G1w, G1b, H1b, qb, h_trans, cterm);
    hipLaunchKernelGGL(k_zero, dim3(4), dim3(256), 0, stream, hist);
    hipLaunchKernelGGL(k_hist, dim3((Nn + 255)/256), dim3(256), 0, stream, seg, hist);
    hipLaunchKernelGGL(k_scan, dim3(1), dim3(1024), 0, stream, hist, offs, cursor);
    hipLaunchKernelGGL(k_scatter, dim3((Nn + 255)/256), dim3(256), 0, stream, seg, cursor, order);
    hipLaunchKernelGGL(k_gemm_fused, dim3(Nn/64), dim3(512), 0, stream,
                       h, wcat, seg, qb, w_score, b_score, cterm, h_trans, e, out);
    hipLaunchKernelGGL(k_ctx, dim3(Cc), dim3(256), 0, stream, h, e, order, hist, offs, ctx);
    hipLaunchKernelGGL(k_vn, dim3(Cc), dim3(256), 0, stream,
                       ctx, g_hat, Wv, bv, H2w, H2b, G2w, G2b, out);
}